// Round 6
// baseline (61.131 us; speedup 1.0000x reference)
//
#include <hip/hip_runtime.h>

// AttEncoder fused: per-channel conv1d encoder + channel attention (C=4).
// Key identity: w[b,i,j,t] = x_i(t)^T M_ij x_j(t), M_ij precomputed from W.
// Only the v-conv is done at full N=512; q/k convs are folded into M (16x16).
//
// R2: FC 64->16, grid 512->2048.  87->65 us.
// R3 FAILED: __launch_bounds__(256,1) -> 1 block/CU, no hiding. 88 us.
// R4: (256,4) VGPR cap 128 + A[b][t][i][j] float4. 60 us.
// R5: 1024-thread blocks (4 KB store runs). 58 us -> run-length theory dead.
//     VALUBusy pinned at ~21% across TLP/VGPR/run-length sweeps => waves are
//     ~77% stalled on something invariant: in-loop W vector-loads share vmcnt
//     with the 4 stores/iter, so each iteration's FMAs wait on prior stores'
//     L2 commit, not just the load.
// R6: stage Wv f-slice (8 KB) in LDS once per block; f-loop = ds_read
//     (lgkmcnt, uniform-addr broadcast, conflict-free) + FMA + stores only.

#define BB 4
#define CC 4
#define LL 32000
#define KK 16
#define ST 8
#define NN 512
#define TT 3999      // (LL-KK)/ST + 1
#define F3 1536
#define FC 32        // f-chunk per block in k2

// ---------------- k0: M[i][j][k][k2] = sum_f Wq[i,f,k] * Wk[j,f,k2] ----------
// Wq[c,f,k] = W[(c*F3 + NN  + f)*KK + k]
// Wk[c,f,k] = W[(c*F3 + 0   + f)*KK + k]
__global__ __launch_bounds__(256) void k0_M(const float* __restrict__ W,
                                            float* __restrict__ M) {
  const int i = blockIdx.x >> 2, j = blockIdx.x & 3;
  __shared__ float wq[NN * KK];   // 32 KB
  __shared__ float wk[NN * KK];   // 32 KB
  const int baseq = (i * F3 + NN) * KK;
  const int basek = (j * F3) * KK;
  for (int idx = threadIdx.x; idx < NN * KK; idx += 256) {
    wq[idx] = W[baseq + idx];
    wk[idx] = W[basek + idx];
  }
  __syncthreads();
  const int k = threadIdx.x >> 4, k2 = threadIdx.x & 15;
  float acc = 0.f;
  for (int f = 0; f < NN; ++f)
    acc = fmaf(wq[f * KK + k], wk[f * KK + k2], acc);
  M[((i * 4 + j) * 16 + k) * 16 + k2] = acc;
}

// ---------------- k1: A[b][t][i][j] = 0.5*(softmax_j(w) + delta_ij) ---------
template <int I>
__device__ __forceinline__ void k1_row(const float xr[4][16],
                                       const float* __restrict__ M,
                                       float* __restrict__ A, int bb, int t) {
  float w[4];
#pragma unroll
  for (int j = 0; j < 4; ++j) {
    const float* Mp = M + (I * 4 + j) * 256;
    float acc = 0.f;
#pragma unroll
    for (int k = 0; k < 16; ++k) {
      float y = 0.f;
#pragma unroll
      for (int k2 = 0; k2 < 16; ++k2)
        y = fmaf(Mp[k * 16 + k2], xr[j][k2], y);
      acc = fmaf(xr[I][k], y, acc);
    }
    w[j] = acc;
  }
  const float m = fmaxf(fmaxf(w[0], w[1]), fmaxf(w[2], w[3]));
  const float e0 = __expf(w[0] - m), e1 = __expf(w[1] - m);
  const float e2 = __expf(w[2] - m), e3 = __expf(w[3] - m);
  const float inv = 0.5f / (e0 + e1 + e2 + e3);
  float4 av;
  av.x = e0 * inv;
  av.y = e1 * inv;
  av.z = e2 * inv;
  av.w = e3 * inv;
  if (I == 0) av.x += 0.5f;
  if (I == 1) av.y += 0.5f;
  if (I == 2) av.z += 0.5f;
  if (I == 3) av.w += 0.5f;
  // A[b][t][i][j], one float4 per (b,t,i)
  *reinterpret_cast<float4*>(A + ((bb * TT + t) * 4 + I) * 4) = av;
}

// block = 256 threads = 4 waves; each wave handles one query row i for the
// same 64 t values (uniform branch per wave, no divergence).
__global__ __launch_bounds__(256, 4) void k1_A(const float* __restrict__ x,
                                               const float* __restrict__ M,
                                               float* __restrict__ A) {
  const int bb = blockIdx.y;
  const int lane = threadIdx.x & 63;
  const int wv = threadIdx.x >> 6;
  const int t = blockIdx.x * 64 + lane;
  if (t >= TT) return;
  float xr[4][16];
#pragma unroll
  for (int c = 0; c < 4; ++c) {
    const float* xp = x + (bb * CC + c) * LL + t * ST;
#pragma unroll
    for (int k4 = 0; k4 < 16; k4 += 4) {
      const float4 v4 = *reinterpret_cast<const float4*>(xp + k4);
      xr[c][k4 + 0] = v4.x;
      xr[c][k4 + 1] = v4.y;
      xr[c][k4 + 2] = v4.z;
      xr[c][k4 + 3] = v4.w;
    }
  }
  if (wv == 0)      k1_row<0>(xr, M, A, bb, t);
  else if (wv == 1) k1_row<1>(xr, M, A, bb, t);
  else if (wv == 2) k1_row<2>(xr, M, A, bb, t);
  else              k1_row<3>(xr, M, A, bb, t);
}

// ---------------- k2: v-conv + mix + store ----------------------------------
// out[b,i,f,t] = sum_j A[b,t,i,j] * v[b,j,f,t],  v[c,f,t] = Wv[c,f,:] . x_c(t)
// Wv[c,f,k] = W[(c*F3 + 2*NN + f)*KK + k]
// R6: Wv f-slice staged in LDS; f-loop has no global loads (stores never
// block a load in vmcnt).
__global__ __launch_bounds__(1024, 4) void k2_out(const float* __restrict__ x,
                                                  const float* __restrict__ W,
                                                  const float* __restrict__ A,
                                                  float* __restrict__ out) {
  __shared__ float wlds[FC * 4 * 16];   // [f][c][k], 8 KB
  const int bb = blockIdx.x >> 2;
  const int t = (blockIdx.x & 3) * 1024 + (int)threadIdx.x;
  const int f0 = blockIdx.y * FC;

  // cooperative stage: 2048 floats / 1024 threads = 2 each
  for (int idx = threadIdx.x; idx < FC * 4 * 16; idx += 1024) {
    const int f = idx >> 6, c = (idx >> 4) & 3, k = idx & 15;
    wlds[idx] = W[(c * F3 + 2 * NN + f0 + f) * KK + k];
  }
  __syncthreads();
  if (t >= TT) return;

  float xr[4][16];
#pragma unroll
  for (int c = 0; c < 4; ++c) {
    const float* xp = x + (bb * CC + c) * LL + t * ST;
#pragma unroll
    for (int k4 = 0; k4 < 16; k4 += 4) {
      const float4 v4 = *reinterpret_cast<const float4*>(xp + k4);
      xr[c][k4 + 0] = v4.x;
      xr[c][k4 + 1] = v4.y;
      xr[c][k4 + 2] = v4.z;
      xr[c][k4 + 3] = v4.w;
    }
  }
  float4 a[4];
  {
    const float4* ap = reinterpret_cast<const float4*>(A + (bb * TT + t) * 16);
#pragma unroll
    for (int i = 0; i < 4; ++i) a[i] = ap[i];
  }

#pragma unroll 2
  for (int f = 0; f < FC; ++f) {
    float v[4];
#pragma unroll
    for (int c = 0; c < 4; ++c) {
      const float4* wc = reinterpret_cast<const float4*>(&wlds[(f * 4 + c) * 16]);
      float acc = 0.f;
#pragma unroll
      for (int k4 = 0; k4 < 4; ++k4) {
        const float4 w4 = wc[k4];
        acc = fmaf(w4.x, xr[c][k4 * 4 + 0], acc);
        acc = fmaf(w4.y, xr[c][k4 * 4 + 1], acc);
        acc = fmaf(w4.z, xr[c][k4 * 4 + 2], acc);
        acc = fmaf(w4.w, xr[c][k4 * 4 + 3], acc);
      }
      v[c] = acc;
    }
    const int fg = f0 + f;
#pragma unroll
    for (int i = 0; i < 4; ++i) {
      const float o = fmaf(a[i].w, v[3],
                           fmaf(a[i].z, v[2],
                                fmaf(a[i].y, v[1], a[i].x * v[0])));
      out[((bb * 4 + i) * NN + fg) * TT + t] = o;
    }
  }
}

extern "C" void kernel_launch(void* const* d_in, const int* in_sizes, int n_in,
                              void* d_out, int out_size, void* d_ws,
                              size_t ws_size, hipStream_t stream) {
  const float* x = (const float*)d_in[0];   // [B, C, L] fp32
  const float* W = (const float*)d_in[1];   // [C, F3, 1, K] fp32
  float* out = (float*)d_out;               // [B, C, N, T] fp32
  float* Mws = (float*)d_ws;                // 4096 floats
  float* Aws = Mws + 4 * 4 * 16 * 16;       // B*T*4*4 floats (~1 MB)

  hipLaunchKernelGGL(k0_M, dim3(16), dim3(256), 0, stream, W, Mws);
  hipLaunchKernelGGL(k1_A, dim3(63, BB), dim3(256), 0, stream, x, Mws, Aws);
  // 16 blocks.x = 4 b * 4 t-tiles (1024 t each); 16 blocks.y = 512/FC f-tiles
  hipLaunchKernelGGL(k2_out, dim3(16, 16), dim3(1024), 0, stream, x, W, Aws,
                     out);
}